// Round 1
// baseline (478.336 us; speedup 1.0000x reference)
//
#include <hip/hip_runtime.h>

#define LL 1024
#define NB 8

// exp(-10*x) = exp2(x * (-10*log2(e)))
__device__ __forceinline__ float exp_n10(float x) {
  return __builtin_amdgcn_exp2f(x * -14.426950408889634f);
}

__global__ __launch_bounds__(1024) void dtw_kernel(const float* __restrict__ outp,
                                                   const float* __restrict__ tgtp,
                                                   float* __restrict__ ws) {
  const int b = blockIdx.x;
  const int t = threadIdx.x;
  const int i = t + 1;                 // DP row 1..1024 (slot index on each anti-diagonal)

  __shared__ float y[LL];
  __shared__ float buf[3][LL + 1];     // three rotating anti-diagonals, slots 0..1024

  // cost[b][i][j] = |output[b][0][i] - target[b][0][j]|
  const float xi = outp[b * LL * LL + t];   // x[i-1]
  y[t] = tgtp[b * LL * LL + t];

  if (t == 0) {
    buf[0][0] = 0.0f;     // diag k=0: D[0,0] = 0
    buf[1][0] = 100.0f;   // diag k=1: D[0,1] = MAX
    buf[1][1] = 100.0f;   // diag k=1: D[1,0] = MAX
  }
  __syncthreads();

  float* p2 = buf[0];
  float* p1 = buf[1];
  float* cu = buf[2];

  float lastv = 0.0f;
  for (int k = 2; k <= 2 * LL; ++k) {
    const int j = k - i;               // column for this thread's slot
    if (j >= 1 && j <= LL) {
      const float a  = p2[i - 1];      // D[i-1, j-1]
      const float bl = p1[i];          // D[i,   j-1]  (already-updated left)
      const float up = p1[i - 1];      // D[i-1, j  ]  (already-updated up)
      const float cost = fabsf(xi - y[j - 1]);
      const float m = (exp_n10(a) + exp_n10(bl) + exp_n10(up)) * (1.0f / 3.0f);
      // -1/rho * log(m + eps) = -0.1*ln2 * log2(m + eps)
      const float v = cost + (-0.069314718055994531f) * __builtin_amdgcn_logf(m + 1e-12f);
      cu[i] = v;
      lastv = v;
    } else if (j == 0) {
      cu[i] = 100.0f;                  // left border D[i,0] = MAX
    }
    if (t == 0) cu[0] = 100.0f;        // top border D[0,j] = MAX
    __syncthreads();
    float* tmp = p2; p2 = p1; p1 = cu; cu = tmp;
  }

  // D[1024,1024] is slot i=1024 on diag k=2048 -> thread t=1023's last interior value
  if (t == LL - 1) ws[b] = lastv;
}

__global__ void reduce_mean(const float* __restrict__ ws, float* __restrict__ out) {
  if (threadIdx.x == 0 && blockIdx.x == 0) {
    float s = 0.0f;
    for (int b = 0; b < NB; ++b) s += ws[b];
    out[0] = s * (1.0f / NB);
  }
}

extern "C" void kernel_launch(void* const* d_in, const int* in_sizes, int n_in,
                              void* d_out, int out_size, void* d_ws, size_t ws_size,
                              hipStream_t stream) {
  const float* o  = (const float*)d_in[0];
  const float* tg = (const float*)d_in[1];
  float* ws  = (float*)d_ws;
  float* out = (float*)d_out;

  dtw_kernel<<<NB, 1024, 0, stream>>>(o, tg, ws);
  reduce_mean<<<1, 64, 0, stream>>>(ws, out);
}